// Round 1
// baseline (463.862 us; speedup 1.0000x reference)
//
#include <hip/hip_runtime.h>

// Weighted BP decoder, (3,6)-regular Tanner graph.
// Check r owns edges 6r..6r+5 (row-major nonzeros of H) -> check-side extrinsic
// products are in-register prefix/suffix products (c_prod_idx unused).
//
// Messages in log2 domain: d = c2v/ln2. With z = exp2(a), t = tanh(a*ln2/2)
// = (z-1)/(z+1); extrinsic product p = A/B with A = prod(z-1), B = prod(z+1)
// (all-but-one). Then
//   d_new = log2(B + kappa*A) - log2(B - kappa*A)
// -> per edge-row transcendentals: exp2 + 2*log2 (tanh/atanh never formed).
// Exponent clamped at 24 (== z <= 2^24): 5-way products <= 2^120, and
// B >= |A| keeps both log args >= (1-kappa)*B > 0.
//
// R6: R5 was latency/barrier-bound, no pipe saturated (VALU 63%, trans ~25%,
// LDS ~37%, occupancy 41.5% == 2 blocks/CU capped by 48 KB LDS). Two fixes,
// both bit-exact vs R5:
//  - ROWS 4 -> 2 (v2f): LDS 49152 -> 24576 B -> 4 blocks/CU (98 KB, 2048 thr
//    = CU max). 32 waves/CU cover the per-iteration barrier + LDS-gather
//    latency that 16 waves could not. __launch_bounds__(T,8) caps VGPR at 64.
//  - LDS slot swizzle swz(s) = rot-right-1 of the low 5 slot bits. Gathers
//    and own-slot writes are stride-6 arithmetic progressions across lanes;
//    with 8B slots the bank-pair group of a raw slot is s&15, and stride 6
//    only reaches the 8 even groups (measured 1.62e7 conflict cycles == 8
//    extra cyc/read). After the rotate the group is (s>>1)&15 which steps by
//    3 (odd) -> 16 consecutive lanes hit 16 distinct groups -> minimum-cycle
//    LDS access. Bijective within every 32-slot chunk (3072 = 96*32); all
//    addresses precomputed at init, zero hot-loop cost.

namespace {

typedef float v2f __attribute__((ext_vector_type(2)));

constexpr int T      = 512;   // threads/block == checks
constexpr int ROWS   = 2;     // batch rows per block (v2f-packed)
constexpr int EEDG   = 3072;
constexpr int NVAR   = 1024;
constexpr int NITER  = 10;
constexpr int BATCH  = 8192;
constexpr int NOUT   = 512;   // N - M outputs per row

constexpr float LOG2E = 1.4426950408889634f;
constexpr float LN2   = 0.6931471805599453f;
constexpr float KAPPA = 0.999995f;
constexpr float ACLMP = 24.0f;   // exp2 arg clamp == z <= 2^24

__device__ __forceinline__ float fast_exp2(float x) { return __builtin_amdgcn_exp2f(x); }
__device__ __forceinline__ float fast_log2(float x) { return __builtin_amdgcn_logf(x); }
__device__ __forceinline__ float fast_rcp (float x) { return __builtin_amdgcn_rcpf(x); }

// Bank-conflict swizzle: rotate low 5 bits of the slot right by 1.
__device__ __forceinline__ int swz(int s) {
    return (s & ~31) | ((s >> 1) & 15) | ((s & 1) << 4);
}

__global__ __launch_bounds__(T, 8)
void bp_decode(const float* __restrict__ llr,
               const float* __restrict__ w_iter,
               const float* __restrict__ llr_iter,
               const float* __restrict__ w_final,
               const float* __restrict__ llr_final,
               const int*  __restrict__ v_sum_idx,
               const int*  __restrict__ edge_var,
               const int*  __restrict__ final_idx,
               float* __restrict__ out)
{
    __shared__ v2f Ad[EEDG];   // 24576 B; 4 blocks/CU co-resident

    const int  tid = threadIdx.x;
    const long b0  = (long)blockIdx.x * ROWS;

    // ---- init: d = 0 (covers all 3072 slots; swizzle is a bijection) ----
    #pragma unroll
    for (int k = 0; k < 6; ++k)
        Ad[k * T + tid] = (v2f)(0.f);

    // ---- static per-thread graph data (my check = tid, edges 6*tid..6*tid+5) ----
    unsigned nbp[6];    // my 12 neighbor LDS slots (swizzled), 2x16b packed
    unsigned varp[3];   // my 6 variable ids, 2x16b packed
    v2f      Lpre[6];   // llr (2 rows) * LOG2E per edge
    int      ows[6];    // my 6 own write slots (swizzled)
    {
        const int4* p = (const int4*)(v_sum_idx + 12 * tid);  // 48B-aligned
        int4 q0 = p[0], q1 = p[1], q2 = p[2];
        nbp[0] = (unsigned)swz(q0.x) | ((unsigned)swz(q0.y) << 16);
        nbp[1] = (unsigned)swz(q0.z) | ((unsigned)swz(q0.w) << 16);
        nbp[2] = (unsigned)swz(q1.x) | ((unsigned)swz(q1.y) << 16);
        nbp[3] = (unsigned)swz(q1.z) | ((unsigned)swz(q1.w) << 16);
        nbp[4] = (unsigned)swz(q2.x) | ((unsigned)swz(q2.y) << 16);
        nbp[5] = (unsigned)swz(q2.z) | ((unsigned)swz(q2.w) << 16);
    }
    #pragma unroll
    for (int j = 0; j < 6; ++j) ows[j] = swz(6 * tid + j);
    {
        int var[6];
        const int2* p = (const int2*)(edge_var + 6 * tid);    // 24B-aligned
        int2 q0 = p[0], q1 = p[1], q2 = p[2];
        var[0]=q0.x; var[1]=q0.y; var[2]=q1.x; var[3]=q1.y; var[4]=q2.x; var[5]=q2.y;
        #pragma unroll
        for (int i = 0; i < 3; ++i)
            varp[i] = (unsigned)var[2*i] | ((unsigned)var[2*i+1] << 16);
        #pragma unroll
        for (int j = 0; j < 6; ++j) {
            v2f L;
            L.x = llr[(b0 + 0) * NVAR + var[j]];
            L.y = llr[(b0 + 1) * NVAR + var[j]];
            Lpre[j] = L * LOG2E;
        }
    }

    // prefetch iteration 0 uniforms
    float w[12], lv[6];
    {
        const float* p = w_iter + 12 * tid;
        float4 a = ((const float4*)p)[0], b = ((const float4*)p)[1], c = ((const float4*)p)[2];
        w[0]=a.x; w[1]=a.y; w[2]=a.z;  w[3]=a.w;
        w[4]=b.x; w[5]=b.y; w[6]=b.z;  w[7]=b.w;
        w[8]=c.x; w[9]=c.y; w[10]=c.z; w[11]=c.w;
        #pragma unroll
        for (int i = 0; i < 3; ++i) {
            unsigned q = varp[i];
            lv[2*i]   = llr_iter[q & 0xffffu];
            lv[2*i+1] = llr_iter[q >> 16];
        }
    }

    __syncthreads();

    #pragma unroll 2
    for (int it = 0; it < NITER; ++it) {
        // accumulators seeded with channel term; LDS gathers folded in
        // immediately (peak live small -> no spills)
        v2f a[6];
        #pragma unroll
        for (int j = 0; j < 6; ++j) a[j] = Lpre[j] * lv[j];
        #pragma unroll
        for (int i = 0; i < 6; ++i) {
            unsigned p  = nbp[i];
            v2f ga = Ad[p & 0xffffu];     // ds_read_b64, conflict-free
            v2f gb = Ad[p >> 16];
            a[i] = a[i] + w[2*i] * ga + w[2*i+1] * gb;   // pk fma
        }

        __syncthreads();   // all gathers landed before anyone overwrites in place

        // prefetch next iteration's uniforms; latency hides under transc phase
        {
            const int itn = (it + 1 < NITER) ? it + 1 : it;   // clamp, no OOB
            const float* p = w_iter + itn * (EEDG * 2) + 12 * tid;
            float4 qa = ((const float4*)p)[0], qb = ((const float4*)p)[1], qc = ((const float4*)p)[2];
            const float* lit = llr_iter + itn * NVAR;
            float lvn[6];
            #pragma unroll
            for (int i = 0; i < 3; ++i) {
                unsigned q = varp[i];
                lvn[2*i]   = lit[q & 0xffffu];
                lvn[2*i+1] = lit[q >> 16];
            }

            // z-domain check update (uses current w, lv via a[])
            v2f zm[6], zp[6];
            #pragma unroll
            for (int j = 0; j < 6; ++j) {
                v2f aa = __builtin_elementwise_min(a[j], (v2f)(ACLMP));
                v2f z;
                z.x = fast_exp2(aa.x);
                z.y = fast_exp2(aa.y);
                zm[j] = z - 1.f;
                zp[j] = z + 1.f;
            }
            v2f A[6], B[6];
            {
                v2f P1=zm[0], P2=P1*zm[1], P3=P2*zm[2], P4=P3*zm[3], P5=P4*zm[4];
                v2f S4=zm[5], S3=S4*zm[4], S2=S3*zm[3], S1=S2*zm[2], S0=S1*zm[1];
                A[0]=S0; A[1]=P1*S1; A[2]=P2*S2; A[3]=P3*S3; A[4]=P4*S4; A[5]=P5;
            }
            {
                v2f P1=zp[0], P2=P1*zp[1], P3=P2*zp[2], P4=P3*zp[3], P5=P4*zp[4];
                v2f S4=zp[5], S3=S4*zp[4], S2=S3*zp[3], S1=S2*zp[2], S0=S1*zp[1];
                B[0]=S0; B[1]=P1*S1; B[2]=P2*S2; B[3]=P3*S3; B[4]=P4*S4; B[5]=P5;
            }
            #pragma unroll
            for (int j = 0; j < 6; ++j) {
                v2f num = KAPPA * A[j] + B[j];    // pk fma
                v2f den = B[j] - KAPPA * A[j];    // pk fma
                v2f d;
                d.x = fast_log2(num.x) - fast_log2(den.x);
                d.y = fast_log2(num.y) - fast_log2(den.y);
                Ad[ows[j]] = d;                   // ds_write_b64, conflict-free
            }

            // rotate prefetched uniforms into place (unroll-2 elides the movs)
            w[0]=qa.x; w[1]=qa.y; w[2]=qa.z;  w[3]=qa.w;
            w[4]=qb.x; w[5]=qb.y; w[6]=qb.z;  w[7]=qb.w;
            w[8]=qc.x; w[9]=qc.y; w[10]=qc.z; w[11]=qc.w;
            #pragma unroll
            for (int j = 0; j < 6; ++j) lv[j] = lvn[j];
        }

        __syncthreads();   // writes visible before next iteration's gathers
    }

    // ---- final marginalization: variable tid (the 512 output vars), 2 rows ----
    {
        int f0 = swz(final_idx[3*tid]), f1 = swz(final_idx[3*tid + 1]), f2 = swz(final_idx[3*tid + 2]);
        v2f d0 = Ad[f0];
        v2f d1 = Ad[f1];
        v2f d2 = Ad[f2];
        float wf0 = w_final[3*tid], wf1 = w_final[3*tid + 1], wf2 = w_final[3*tid + 2];
        float lf  = llr_final[tid];
        v2f l;
        l.x = llr[(b0 + 0) * NVAR + tid];
        l.y = llr[(b0 + 1) * NVAR + tid];

        v2f fin = (d0 * wf0 + d1 * wf1 + d2 * wf2) * LN2;   // c2v = ln2 * d
        v2f v   = l * lf + fin;
        out[(b0 + 0) * NOUT + tid] = fast_rcp(1.f + fast_exp2(-v.x * LOG2E));
        out[(b0 + 1) * NOUT + tid] = fast_rcp(1.f + fast_exp2(-v.y * LOG2E));
    }
}

} // namespace

extern "C" void kernel_launch(void* const* d_in, const int* in_sizes, int n_in,
                              void* d_out, int out_size, void* d_ws, size_t ws_size,
                              hipStream_t stream)
{
    const float* llr       = (const float*)d_in[0];
    const float* w_iter    = (const float*)d_in[1];
    const float* llr_iter  = (const float*)d_in[2];
    const float* w_final   = (const float*)d_in[3];
    const float* llr_final = (const float*)d_in[4];
    const int*   v_sum_idx = (const int*)d_in[5];
    // d_in[6] = c_prod_idx: unused (check groups are consecutive by construction)
    const int*   edge_var  = (const int*)d_in[7];
    const int*   final_idx = (const int*)d_in[8];
    float* outp = (float*)d_out;

    dim3 grid(BATCH / ROWS), block(T);
    hipLaunchKernelGGL(bp_decode, grid, block, 0, stream,
                       llr, w_iter, llr_iter, w_final, llr_final,
                       v_sum_idx, edge_var, final_idx, outp);
}

// Round 2
// 231.929 us; speedup vs baseline: 2.0000x; 2.0000x over previous
//
#include <hip/hip_runtime.h>

// Weighted BP decoder, (3,6)-regular Tanner graph.
// Check r owns edges 6r..6r+5 (row-major nonzeros of H) -> check-side extrinsic
// products are in-register prefix/suffix products (c_prod_idx unused).
//
// Messages in log2 domain: d = c2v/ln2. With z = exp2(a), t = tanh(a*ln2/2)
// = (z-1)/(z+1); extrinsic product p = A/B with A = prod(z-1), B = prod(z+1)
// (all-but-one). Then
//   d_new = log2(B + kappa*A) - log2(B - kappa*A)
// -> per edge-row transcendentals: exp2 + 2*log2 (tanh/atanh never formed).
// Exponent clamped at 24 (== z <= 2^24): 5-way products <= 2^120, and
// B >= |A| keeps both log args >= (1-kappa)*B > 0.
//
// R7: R6 with the launch-bounds spill fixed.
//  - R6 post-mortem: __launch_bounds__(512, 8) was interpreted with CUDA
//    blocks-per-CU semantics by hipcc: 8 blocks x 8 waves = 64 waves ->
//    VGPR cap 2048/64 = 32 (measured VGPR_Count=32) -> whole working set
//    spilled to scratch: FETCH 884 MB / WRITE 426 MB of HBM spill traffic,
//    402 us. Cross-check: R5's (T,2) -> 16 waves -> cap 128, used 64.
//  - R6 DID prove 4 blocks/CU co-reside at LDS=24576 (occupancy ~90%), so
//    the ROWS=2 occupancy plan stands. This round: __launch_bounds__(T, 4)
//    -> 4 blocks x 8 waves = 32 waves -> cap 64 VGPRs, same cap R5 fit with
//    double the vector state. ROWS=2 needs ~50 -> no spill.
//  - Own-write slots packed 2x16b (3 regs instead of 6) for extra margin.
//  - Bank swizzle kept: with b64 accesses restored (no pressure-driven b32
//    split), stride-6 slot progressions hit all 16 bank-pair groups per 16
//    lanes -> conflict-free gathers and writes.

namespace {

typedef float v2f __attribute__((ext_vector_type(2)));

constexpr int T      = 512;   // threads/block == checks
constexpr int ROWS   = 2;     // batch rows per block (v2f-packed)
constexpr int EEDG   = 3072;
constexpr int NVAR   = 1024;
constexpr int NITER  = 10;
constexpr int BATCH  = 8192;
constexpr int NOUT   = 512;   // N - M outputs per row

constexpr float LOG2E = 1.4426950408889634f;
constexpr float LN2   = 0.6931471805599453f;
constexpr float KAPPA = 0.999995f;
constexpr float ACLMP = 24.0f;   // exp2 arg clamp == z <= 2^24

__device__ __forceinline__ float fast_exp2(float x) { return __builtin_amdgcn_exp2f(x); }
__device__ __forceinline__ float fast_log2(float x) { return __builtin_amdgcn_logf(x); }
__device__ __forceinline__ float fast_rcp (float x) { return __builtin_amdgcn_rcpf(x); }

// Bank-conflict swizzle: rotate low 5 bits of the slot right by 1.
__device__ __forceinline__ int swz(int s) {
    return (s & ~31) | ((s >> 1) & 15) | ((s & 1) << 4);
}

__global__ __launch_bounds__(T, 4)   // 4 blocks/CU * 8 waves = 32 waves -> VGPR cap 64
void bp_decode(const float* __restrict__ llr,
               const float* __restrict__ w_iter,
               const float* __restrict__ llr_iter,
               const float* __restrict__ w_final,
               const float* __restrict__ llr_final,
               const int*  __restrict__ v_sum_idx,
               const int*  __restrict__ edge_var,
               const int*  __restrict__ final_idx,
               float* __restrict__ out)
{
    __shared__ v2f Ad[EEDG];   // 24576 B; 4 blocks/CU co-resident (proven in R6)

    const int  tid = threadIdx.x;
    const long b0  = (long)blockIdx.x * ROWS;

    // ---- init: d = 0 (covers all 3072 slots; swizzle is a bijection) ----
    #pragma unroll
    for (int k = 0; k < 6; ++k)
        Ad[k * T + tid] = (v2f)(0.f);

    // ---- static per-thread graph data (my check = tid, edges 6*tid..6*tid+5) ----
    unsigned nbp[6];    // my 12 neighbor LDS slots (swizzled), 2x16b packed
    unsigned varp[3];   // my 6 variable ids, 2x16b packed
    unsigned owp[3];    // my 6 own write slots (swizzled), 2x16b packed
    v2f      Lpre[6];   // llr (2 rows) * LOG2E per edge
    {
        const int4* p = (const int4*)(v_sum_idx + 12 * tid);  // 48B-aligned
        int4 q0 = p[0], q1 = p[1], q2 = p[2];
        nbp[0] = (unsigned)swz(q0.x) | ((unsigned)swz(q0.y) << 16);
        nbp[1] = (unsigned)swz(q0.z) | ((unsigned)swz(q0.w) << 16);
        nbp[2] = (unsigned)swz(q1.x) | ((unsigned)swz(q1.y) << 16);
        nbp[3] = (unsigned)swz(q1.z) | ((unsigned)swz(q1.w) << 16);
        nbp[4] = (unsigned)swz(q2.x) | ((unsigned)swz(q2.y) << 16);
        nbp[5] = (unsigned)swz(q2.z) | ((unsigned)swz(q2.w) << 16);
    }
    #pragma unroll
    for (int i = 0; i < 3; ++i)
        owp[i] = (unsigned)swz(6 * tid + 2 * i) | ((unsigned)swz(6 * tid + 2 * i + 1) << 16);
    {
        int var[6];
        const int2* p = (const int2*)(edge_var + 6 * tid);    // 24B-aligned
        int2 q0 = p[0], q1 = p[1], q2 = p[2];
        var[0]=q0.x; var[1]=q0.y; var[2]=q1.x; var[3]=q1.y; var[4]=q2.x; var[5]=q2.y;
        #pragma unroll
        for (int i = 0; i < 3; ++i)
            varp[i] = (unsigned)var[2*i] | ((unsigned)var[2*i+1] << 16);
        #pragma unroll
        for (int j = 0; j < 6; ++j) {
            v2f L;
            L.x = llr[(b0 + 0) * NVAR + var[j]];
            L.y = llr[(b0 + 1) * NVAR + var[j]];
            Lpre[j] = L * LOG2E;
        }
    }

    // prefetch iteration 0 uniforms
    float w[12], lv[6];
    {
        const float* p = w_iter + 12 * tid;
        float4 a = ((const float4*)p)[0], b = ((const float4*)p)[1], c = ((const float4*)p)[2];
        w[0]=a.x; w[1]=a.y; w[2]=a.z;  w[3]=a.w;
        w[4]=b.x; w[5]=b.y; w[6]=b.z;  w[7]=b.w;
        w[8]=c.x; w[9]=c.y; w[10]=c.z; w[11]=c.w;
        #pragma unroll
        for (int i = 0; i < 3; ++i) {
            unsigned q = varp[i];
            lv[2*i]   = llr_iter[q & 0xffffu];
            lv[2*i+1] = llr_iter[q >> 16];
        }
    }

    __syncthreads();

    #pragma unroll 2
    for (int it = 0; it < NITER; ++it) {
        // accumulators seeded with channel term; LDS gathers folded in
        // immediately (peak live small -> no spills)
        v2f a[6];
        #pragma unroll
        for (int j = 0; j < 6; ++j) a[j] = Lpre[j] * lv[j];
        #pragma unroll
        for (int i = 0; i < 6; ++i) {
            unsigned p  = nbp[i];
            v2f ga = Ad[p & 0xffffu];     // ds_read_b64, conflict-free
            v2f gb = Ad[p >> 16];
            a[i] = a[i] + w[2*i] * ga + w[2*i+1] * gb;   // pk fma
        }

        __syncthreads();   // all gathers landed before anyone overwrites in place

        // prefetch next iteration's uniforms; latency hides under transc phase
        {
            const int itn = (it + 1 < NITER) ? it + 1 : it;   // clamp, no OOB
            const float* p = w_iter + itn * (EEDG * 2) + 12 * tid;
            float4 qa = ((const float4*)p)[0], qb = ((const float4*)p)[1], qc = ((const float4*)p)[2];
            const float* lit = llr_iter + itn * NVAR;
            float lvn[6];
            #pragma unroll
            for (int i = 0; i < 3; ++i) {
                unsigned q = varp[i];
                lvn[2*i]   = lit[q & 0xffffu];
                lvn[2*i+1] = lit[q >> 16];
            }

            // z-domain check update (uses current w, lv via a[])
            v2f zm[6], zp[6];
            #pragma unroll
            for (int j = 0; j < 6; ++j) {
                v2f aa = __builtin_elementwise_min(a[j], (v2f)(ACLMP));
                v2f z;
                z.x = fast_exp2(aa.x);
                z.y = fast_exp2(aa.y);
                zm[j] = z - 1.f;
                zp[j] = z + 1.f;
            }
            v2f A[6], B[6];
            {
                v2f P1=zm[0], P2=P1*zm[1], P3=P2*zm[2], P4=P3*zm[3], P5=P4*zm[4];
                v2f S4=zm[5], S3=S4*zm[4], S2=S3*zm[3], S1=S2*zm[2], S0=S1*zm[1];
                A[0]=S0; A[1]=P1*S1; A[2]=P2*S2; A[3]=P3*S3; A[4]=P4*S4; A[5]=P5;
            }
            {
                v2f P1=zp[0], P2=P1*zp[1], P3=P2*zp[2], P4=P3*zp[3], P5=P4*zp[4];
                v2f S4=zp[5], S3=S4*zp[4], S2=S3*zp[3], S1=S2*zp[2], S0=S1*zp[1];
                B[0]=S0; B[1]=P1*S1; B[2]=P2*S2; B[3]=P3*S3; B[4]=P4*S4; B[5]=P5;
            }
            #pragma unroll
            for (int j = 0; j < 6; ++j) {
                v2f num = KAPPA * A[j] + B[j];    // pk fma
                v2f den = B[j] - KAPPA * A[j];    // pk fma
                v2f d;
                d.x = fast_log2(num.x) - fast_log2(den.x);
                d.y = fast_log2(num.y) - fast_log2(den.y);
                unsigned o = owp[j >> 1];
                Ad[(j & 1) ? (o >> 16) : (o & 0xffffu)] = d;   // ds_write_b64, conflict-free
            }

            // rotate prefetched uniforms into place (unroll-2 elides the movs)
            w[0]=qa.x; w[1]=qa.y; w[2]=qa.z;  w[3]=qa.w;
            w[4]=qb.x; w[5]=qb.y; w[6]=qb.z;  w[7]=qb.w;
            w[8]=qc.x; w[9]=qc.y; w[10]=qc.z; w[11]=qc.w;
            #pragma unroll
            for (int j = 0; j < 6; ++j) lv[j] = lvn[j];
        }

        __syncthreads();   // writes visible before next iteration's gathers
    }

    // ---- final marginalization: variable tid (the 512 output vars), 2 rows ----
    {
        int f0 = swz(final_idx[3*tid]), f1 = swz(final_idx[3*tid + 1]), f2 = swz(final_idx[3*tid + 2]);
        v2f d0 = Ad[f0];
        v2f d1 = Ad[f1];
        v2f d2 = Ad[f2];
        float wf0 = w_final[3*tid], wf1 = w_final[3*tid + 1], wf2 = w_final[3*tid + 2];
        float lf  = llr_final[tid];
        v2f l;
        l.x = llr[(b0 + 0) * NVAR + tid];
        l.y = llr[(b0 + 1) * NVAR + tid];

        v2f fin = (d0 * wf0 + d1 * wf1 + d2 * wf2) * LN2;   // c2v = ln2 * d
        v2f v   = l * lf + fin;
        out[(b0 + 0) * NOUT + tid] = fast_rcp(1.f + fast_exp2(-v.x * LOG2E));
        out[(b0 + 1) * NOUT + tid] = fast_rcp(1.f + fast_exp2(-v.y * LOG2E));
    }
}

} // namespace

extern "C" void kernel_launch(void* const* d_in, const int* in_sizes, int n_in,
                              void* d_out, int out_size, void* d_ws, size_t ws_size,
                              hipStream_t stream)
{
    const float* llr       = (const float*)d_in[0];
    const float* w_iter    = (const float*)d_in[1];
    const float* llr_iter  = (const float*)d_in[2];
    const float* w_final   = (const float*)d_in[3];
    const float* llr_final = (const float*)d_in[4];
    const int*   v_sum_idx = (const int*)d_in[5];
    // d_in[6] = c_prod_idx: unused (check groups are consecutive by construction)
    const int*   edge_var  = (const int*)d_in[7];
    const int*   final_idx = (const int*)d_in[8];
    float* outp = (float*)d_out;

    dim3 grid(BATCH / ROWS), block(T);
    hipLaunchKernelGGL(bp_decode, grid, block, 0, stream,
                       llr, w_iter, llr_iter, w_final, llr_final,
                       v_sum_idx, edge_var, final_idx, outp);
}